// Round 7
// baseline (3470.612 us; speedup 1.0000x reference)
//
#include <hip/hip_runtime.h>

// ---------------------------------------------------------------------------
// BasicBahdanauAttnDecoder: T=64 B=32 S=64 V=32000 E=512 H=512
// Round 7: multi-launch scan — the grid barrier is replaced by kernel
// boundaries (hardware-managed sync + coherence). 3 kernels per step:
//   kA: gates0+cell0 (32 WGs, col-sliced)
//   kB: gates1+cell1 (32 WGs, col-sliced)
//   kC: per-batch hs GEMV (WhT, L2-resident) + attention + context
// No flags, no bypass asm, no spin loops. State in global, double-buffered h.
// ---------------------------------------------------------------------------

typedef unsigned short u16;
typedef short bf16x8 __attribute__((ext_vector_type(8)));
typedef float f32x4 __attribute__((ext_vector_type(4)));

#define MFMA_BF16(a, b, c) __builtin_amdgcn_mfma_f32_16x16x32_bf16((a), (b), (c), 0, 0, 0)

struct __attribute__((aligned(8))) U16x4 { u16 x, y, z, w; };

__device__ __forceinline__ float b2f(u16 u) {
  unsigned v = ((unsigned)u) << 16; float f; __builtin_memcpy(&f, &v, 4); return f;
}
__device__ __forceinline__ u16 f2b(float f) {
  unsigned u; __builtin_memcpy(&u, &f, 4);
  u = (u + 0x7FFFu + ((u >> 16) & 1u)) >> 16;
  return (u16)u;
}
__device__ __forceinline__ float sigm(float x) { return 1.f / (1.f + __expf(-x)); }
__device__ __forceinline__ float tanh_fast(float x) {
  x = fminf(fmaxf(x, -15.f), 15.f);
  float e = __expf(2.f * x);
  return (e - 1.f) / (e + 1.f);
}

// ---------------------------------------------------------------------------
// prep kernels
// ---------------------------------------------------------------------------
__global__ void f2b4_kernel(const float* __restrict__ src, u16* __restrict__ dst, long n4) {
  long i = (long)blockIdx.x * blockDim.x + threadIdx.x;
  long stride = (long)gridDim.x * blockDim.x;
  for (; i < n4; i += stride) {
    float4 v = ((const float4*)src)[i];
    U16x4 o; o.x = f2b(v.x); o.y = f2b(v.y); o.z = f2b(v.z); o.w = f2b(v.w);
    ((U16x4*)dst)[i] = o;
  }
}

__global__ void f2b4_strided(const float* __restrict__ src, u16* __restrict__ dst,
                             int rows, int cols4, int sld, int soff, int dld, int doff) {
  int total = rows * cols4;
  for (int i = blockIdx.x * blockDim.x + threadIdx.x; i < total; i += gridDim.x * blockDim.x) {
    int r = i / cols4, c4 = i - r * cols4;
    float4 v = *(const float4*)(src + (size_t)r * sld + soff + c4 * 4);
    U16x4 o; o.x = f2b(v.x); o.y = f2b(v.y); o.z = f2b(v.z); o.w = f2b(v.w);
    *(U16x4*)(dst + (size_t)r * dld + doff + c4 * 4) = o;
  }
}

__global__ void gather_emb_kernel(const int* __restrict__ trg, const float* __restrict__ emb,
                                  u16* __restrict__ out) {
  int r = blockIdx.x;
  int v = trg[r];
  const float* srow = emb + (size_t)v * 512;
  u16* drow = out + (size_t)r * 512;
  for (int e = threadIdx.x; e < 128; e += blockDim.x) {
    float4 x = ((const float4*)srow)[e];
    U16x4 o; o.x = f2b(x.x); o.y = f2b(x.y); o.z = f2b(x.z); o.w = f2b(x.w);
    ((U16x4*)drow)[e] = o;
  }
}

__global__ void annot_tr_kernel(const float* __restrict__ annot, u16* __restrict__ abt) {
  int b = blockIdx.x >> 6, s = blockIdx.x & 63;
  const float* src = annot + (size_t)(s * 32 + b) * 512;
  u16* dst = abt + (size_t)(b * 64 + s) * 512;
  int j = threadIdx.x;
  float4 v = ((const float4*)src)[j];
  U16x4 o; o.x = f2b(v.x); o.y = f2b(v.y); o.z = f2b(v.z); o.w = f2b(v.w);
  ((U16x4*)dst)[j] = o;
}

__global__ void enc_tr_kernel(const float* __restrict__ enc, u16* __restrict__ ebt) {
  int b = blockIdx.x >> 6, s = blockIdx.x & 63;
  const float* src = enc + (size_t)(s * 32 + b) * 1024;
  u16* dst = ebt + (size_t)(b * 64 + s) * 1024;
  int j = threadIdx.x;
  float4 v = ((const float4*)src)[j];
  U16x4 o; o.x = f2b(v.x); o.y = f2b(v.y); o.z = f2b(v.z); o.w = f2b(v.w);
  ((U16x4*)dst)[j] = o;
}

// WhT[k][n] = bf16(Wh[n][k])  (k-major for coalesced GEMV)
__global__ void whT_kernel(const float* __restrict__ Wh, u16* __restrict__ WhT) {
  int k = blockIdx.x, n = threadIdx.x;  // 512 blocks x 512 threads
  WhT[(size_t)k * 512 + n] = f2b(Wh[(size_t)n * 512 + k]);
}

// ---------------------------------------------------------------------------
// generic bf16 GEMM (unchanged)
// ---------------------------------------------------------------------------
template <int MODE>
__global__ __launch_bounds__(256) void gemm_bt(
    const u16* __restrict__ A, const u16* __restrict__ B,
    float* __restrict__ outF, u16* __restrict__ outB,
    const float* __restrict__ bias0, const float* __restrict__ bias1,
    int N, int K, int ntiles, float* __restrict__ pmax, float* __restrict__ psum) {
  const int l = threadIdx.x & 63, wv = threadIdx.x >> 6;
  const int m0 = blockIdx.x * 128 + wv * 32;
  const int n0 = blockIdx.y * 64;
  const int kg = ((l >> 4) << 3);
  const u16* Ap0 = A + (size_t)(m0 + (l & 15)) * K + kg;
  const u16* Ap1 = Ap0 + (size_t)16 * K;
  const u16* Bp = B + (size_t)(n0 + (l & 15)) * K + kg;
  f32x4 acc[2][4] = {};
  for (int k0 = 0; k0 < K; k0 += 32) {
    bf16x8 a0 = *(const bf16x8*)(Ap0 + k0);
    bf16x8 a1 = *(const bf16x8*)(Ap1 + k0);
#pragma unroll
    for (int nf = 0; nf < 4; ++nf) {
      bf16x8 bb = *(const bf16x8*)(Bp + (size_t)(nf * 16) * K + k0);
      acc[0][nf] = MFMA_BF16(a0, bb, acc[0][nf]);
      acc[1][nf] = MFMA_BF16(a1, bb, acc[1][nf]);
    }
  }
  float biasv[4];
#pragma unroll
  for (int nf = 0; nf < 4; ++nf) {
    int col = n0 + nf * 16 + (l & 15);
    float bv = bias0 ? bias0[col] : 0.f;
    if (bias1) bv += bias1[col];
    biasv[nf] = bv;
  }
#pragma unroll
  for (int mi = 0; mi < 2; ++mi)
#pragma unroll
    for (int nf = 0; nf < 4; ++nf)
#pragma unroll
      for (int i = 0; i < 4; ++i) acc[mi][nf][i] += biasv[nf];

#pragma unroll
  for (int mi = 0; mi < 2; ++mi)
#pragma unroll
    for (int i = 0; i < 4; ++i) {
      int row = m0 + mi * 16 + ((l >> 4) << 2) + i;
#pragma unroll
      for (int nf = 0; nf < 4; ++nf) {
        int col = n0 + nf * 16 + (l & 15);
        if constexpr (MODE == 1)
          outB[(size_t)row * N + col] = f2b(acc[mi][nf][i]);
        else
          outF[(size_t)row * N + col] = acc[mi][nf][i];
      }
    }
  if constexpr (MODE == 2) {
    float lm[2][4], se[2][4];
#pragma unroll
    for (int mi = 0; mi < 2; ++mi)
#pragma unroll
      for (int i = 0; i < 4; ++i) {
        float m_ = acc[mi][0][i];
#pragma unroll
        for (int nf = 1; nf < 4; ++nf) m_ = fmaxf(m_, acc[mi][nf][i]);
        lm[mi][i] = m_;
      }
#pragma unroll
    for (int d = 1; d < 16; d <<= 1)
#pragma unroll
      for (int mi = 0; mi < 2; ++mi)
#pragma unroll
        for (int i = 0; i < 4; ++i) lm[mi][i] = fmaxf(lm[mi][i], __shfl_xor(lm[mi][i], d));
#pragma unroll
    for (int mi = 0; mi < 2; ++mi)
#pragma unroll
      for (int i = 0; i < 4; ++i) {
        float s_ = 0.f;
#pragma unroll
        for (int nf = 0; nf < 4; ++nf) s_ += __expf(acc[mi][nf][i] - lm[mi][i]);
        se[mi][i] = s_;
      }
#pragma unroll
    for (int d = 1; d < 16; d <<= 1)
#pragma unroll
      for (int mi = 0; mi < 2; ++mi)
#pragma unroll
        for (int i = 0; i < 4; ++i) se[mi][i] += __shfl_xor(se[mi][i], d);
    if ((l & 15) == 0) {
#pragma unroll
      for (int mi = 0; mi < 2; ++mi)
#pragma unroll
        for (int i = 0; i < 4; ++i) {
          int row = m0 + mi * 16 + ((l >> 4) << 2) + i;
          pmax[(size_t)row * ntiles + blockIdx.y] = lm[mi][i];
          psum[(size_t)row * ntiles + blockIdx.y] = se[mi][i];
        }
    }
  }
}

// ---------------------------------------------------------------------------
// kA: gates0 + LSTM cell 0. 32 WGs x 512 threads, col-sliced (16 cols/gate).
// ---------------------------------------------------------------------------
__global__ __launch_bounds__(512) void kA(
    const u16* __restrict__ xW0, const u16* __restrict__ Wcat0,
    const u16* __restrict__ ctxb, const u16* __restrict__ h0_in,
    u16* __restrict__ h0_out, float* __restrict__ c0,
    float* __restrict__ dout_hc, int t) {
  __shared__ float sm[8 * 32 * 68];  // stride-68 staging (conflict-light)
  const int w = blockIdx.x, tid = threadIdx.x;
  const int l = tid & 63, wv = tid >> 6;
  const int jh0 = w * 16;
  const int kg = (l >> 4) << 3;

  f32x4 acc[2][4] = {};
#pragma unroll
  for (int kk = 0; kk < 6; ++kk) {
    const int k0 = wv * 192 + kk * 32;
    const u16* ab; int ld, off;
    if (k0 < 1024) { ab = ctxb; ld = 1024; off = k0; }
    else { ab = h0_in; ld = 512; off = k0 - 1024; }
    bf16x8 a0 = *(const bf16x8*)(ab + (size_t)(l & 15) * ld + off + kg);
    bf16x8 a1 = *(const bf16x8*)(ab + (size_t)((l & 15) + 16) * ld + off + kg);
#pragma unroll
    for (int q = 0; q < 4; ++q) {
      bf16x8 bb = *(const bf16x8*)(Wcat0 + (size_t)(q * 512 + jh0 + (l & 15)) * 1536 + k0 + kg);
      acc[0][q] = MFMA_BF16(a0, bb, acc[0][q]);
      acc[1][q] = MFMA_BF16(a1, bb, acc[1][q]);
    }
  }
#pragma unroll
  for (int mi = 0; mi < 2; ++mi)
#pragma unroll
    for (int q = 0; q < 4; ++q)
#pragma unroll
      for (int i = 0; i < 4; ++i) {
        int m = mi * 16 + ((l >> 4) << 2) + i;
        sm[(wv * 32 + m) * 68 + q * 16 + (l & 15)] = acc[mi][q][i];
      }
  __syncthreads();
  {
    const int b = tid >> 4, jl = tid & 15, jh = jh0 + jl;
    float gate[4];
#pragma unroll
    for (int q = 0; q < 4; ++q) {
      float s = 0.f;
#pragma unroll
      for (int kv = 0; kv < 8; ++kv) s += sm[(kv * 32 + b) * 68 + q * 16 + jl];
      gate[q] = s + b2f(xW0[(size_t)(t * 32 + b) * 2048 + q * 512 + jh]);
    }
    float cn = sigm(gate[1]) * c0[b * 512 + jh] + sigm(gate[0]) * tanh_fast(gate[2]);
    float hn = sigm(gate[3]) * tanh_fast(cn);
    c0[b * 512 + jh] = cn;
    unsigned hb = f2b(hn);
    unsigned hi = __shfl_down(hb, 1);
    if (!(jl & 1)) *(unsigned*)(h0_out + b * 512 + jh) = hb | (hi << 16);
    if (t == 63) { dout_hc[b * 512 + jh] = hn; dout_hc[32768 + b * 512 + jh] = cn; }
  }
}

// ---------------------------------------------------------------------------
// kB: gates1 + LSTM cell 1. 32 WGs x 512 threads, col-sliced.
// ---------------------------------------------------------------------------
__global__ __launch_bounds__(512) void kB(
    const u16* __restrict__ Wcat1, const u16* __restrict__ h0_new,
    const u16* __restrict__ h1_in, u16* __restrict__ h1_out,
    float* __restrict__ c1, const float* __restrict__ b_ih1,
    const float* __restrict__ b_hh1, u16* __restrict__ scoresb,
    float* __restrict__ dout_hc, int t) {
  __shared__ float sm[8 * 32 * 68];
  const int w = blockIdx.x, tid = threadIdx.x;
  const int l = tid & 63, wv = tid >> 6;
  const int jh0 = w * 16;
  const int kg = (l >> 4) << 3;

  f32x4 acc[2][4] = {};
#pragma unroll
  for (int kk = 0; kk < 4; ++kk) {
    const int k0 = wv * 128 + kk * 32;
    const u16* ab; int off;
    if (k0 < 512) { ab = h0_new; off = k0; }
    else { ab = h1_in; off = k0 - 512; }
    bf16x8 a0 = *(const bf16x8*)(ab + (size_t)(l & 15) * 512 + off + kg);
    bf16x8 a1 = *(const bf16x8*)(ab + (size_t)((l & 15) + 16) * 512 + off + kg);
#pragma unroll
    for (int q = 0; q < 4; ++q) {
      bf16x8 bb = *(const bf16x8*)(Wcat1 + (size_t)(q * 512 + jh0 + (l & 15)) * 1024 + k0 + kg);
      acc[0][q] = MFMA_BF16(a0, bb, acc[0][q]);
      acc[1][q] = MFMA_BF16(a1, bb, acc[1][q]);
    }
  }
#pragma unroll
  for (int mi = 0; mi < 2; ++mi)
#pragma unroll
    for (int q = 0; q < 4; ++q)
#pragma unroll
      for (int i = 0; i < 4; ++i) {
        int m = mi * 16 + ((l >> 4) << 2) + i;
        sm[(wv * 32 + m) * 68 + q * 16 + (l & 15)] = acc[mi][q][i];
      }
  __syncthreads();
  {
    const int b = tid >> 4, jl = tid & 15, jh = jh0 + jl;
    float gate[4];
#pragma unroll
    for (int q = 0; q < 4; ++q) {
      float s = 0.f;
#pragma unroll
      for (int kv = 0; kv < 8; ++kv) s += sm[(kv * 32 + b) * 68 + q * 16 + jl];
      gate[q] = s + b_ih1[q * 512 + jh] + b_hh1[q * 512 + jh];
    }
    float cn = sigm(gate[1]) * c1[b * 512 + jh] + sigm(gate[0]) * tanh_fast(gate[2]);
    float hn = sigm(gate[3]) * tanh_fast(cn);
    c1[b * 512 + jh] = cn;
    unsigned hb = f2b(hn);
    unsigned hi = __shfl_down(hb, 1);
    if (!(jl & 1)) {
      unsigned pk = hb | (hi << 16);
      *(unsigned*)(h1_out + b * 512 + jh) = pk;
      *(unsigned*)(scoresb + (size_t)(t * 32 + b) * 1536 + jh) = pk;
    }
    if (t == 63) { dout_hc[16384 + b * 512 + jh] = hn; dout_hc[49152 + b * 512 + jh] = cn; }
  }
}

// ---------------------------------------------------------------------------
// kC: per-batch (blockIdx = b): hs = h1[b] @ Wh^T + bh (GEMV on WhT, in LDS),
// then attention scores, softmax over S=64, context, ctx/scores writes.
// ---------------------------------------------------------------------------
__global__ __launch_bounds__(512) void kC(
    const u16* __restrict__ WhT,      // [512 k][512 n] bf16
    const float* __restrict__ bh, const float* __restrict__ Wo,
    const float* __restrict__ bo,
    const u16* __restrict__ annot_bt, // [32][64][512] bf16
    const u16* __restrict__ enc_bt,   // [32][64][1024] bf16
    const u16* __restrict__ h1_new,   // [32][512] bf16
    u16* __restrict__ ctxb,           // [32][1024] bf16
    u16* __restrict__ scoresb, int t) {
  __shared__ float h1f[512];
  __shared__ float hsv[512];
  __shared__ float wo_s[512];
  __shared__ float red[512];
  __shared__ float a_s[64];
  const int b = blockIdx.x, tid = threadIdx.x;

  h1f[tid] = b2f(h1_new[b * 512 + tid]);
  wo_s[tid] = Wo[tid];
  __syncthreads();

  // hs GEMV: thread n computes dot(h1, WhT[:, n]) — coalesced WhT reads,
  // LDS broadcast reads of h1f (same address across the wave: conflict-free).
  {
    float acc = 0.f;
    const u16* wp = WhT + tid;
#pragma unroll 8
    for (int k = 0; k < 512; ++k) acc += h1f[k] * b2f(wp[(size_t)k * 512]);
    hsv[tid] = acc + bh[tid];
  }
  __syncthreads();

  // attention energies: e[s] = tanh(hs + annot[s]) . Wo + bo, 8 threads/s
  const int s_ = tid >> 3, ks = tid & 7;
  {
    const u16* arow = annot_bt + (size_t)(b * 64 + s_) * 512 + ks * 64;
    float accv = 0.f;
#pragma unroll
    for (int kk8 = 0; kk8 < 8; ++kk8) {
      bf16x8 av = *(const bf16x8*)(arow + kk8 * 8);
#pragma unroll
      for (int j = 0; j < 8; ++j) {
        int k = ks * 64 + kk8 * 8 + j;
        accv += tanh_fast(hsv[k] + b2f((u16)av[j])) * wo_s[k];
      }
    }
    red[tid] = accv;
  }
  __syncthreads();
  if (tid < 64) {
    float e = bo[0];
#pragma unroll
    for (int j = 0; j < 8; ++j) e += red[tid * 8 + j];
    float mx = e;
#pragma unroll
    for (int d = 1; d < 64; d <<= 1) mx = fmaxf(mx, __shfl_xor(mx, d));
    float p = __expf(e - mx);
    float ss = p;
#pragma unroll
    for (int d = 1; d < 64; d <<= 1) ss += __shfl_xor(ss, d);
    a_s[tid] = p / ss;
  }
  __syncthreads();
  float cx0 = 0.f, cx1 = 0.f;
  const u16* erow = enc_bt + (size_t)b * 65536 + tid * 2;
#pragma unroll 8
  for (int s2 = 0; s2 < 64; ++s2) {
    unsigned ev = *(const unsigned*)(erow + (size_t)s2 * 1024);
    float av = a_s[s2];
    cx0 += av * b2f((u16)(ev & 0xFFFFu));
    cx1 += av * b2f((u16)(ev >> 16));
  }
  unsigned pk = (unsigned)f2b(cx0) | ((unsigned)f2b(cx1) << 16);
  *(unsigned*)(ctxb + b * 1024 + tid * 2) = pk;
  *(unsigned*)(scoresb + (size_t)(t * 32 + b) * 1536 + 512 + tid * 2) = pk;
}

// ---------------------------------------------------------------------------
// logsumexp combine + finalize (unchanged)
// ---------------------------------------------------------------------------
__global__ __launch_bounds__(256) void lse_kernel(const float* __restrict__ pmax,
                                                  const float* __restrict__ psum,
                                                  float* __restrict__ lse, int nt) {
  __shared__ float red[256];
  const int r = blockIdx.x;
  float m = -3.4e38f;
  for (int j = threadIdx.x; j < nt; j += 256) m = fmaxf(m, pmax[(size_t)r * nt + j]);
  red[threadIdx.x] = m; __syncthreads();
  for (int s = 128; s > 0; s >>= 1) {
    if (threadIdx.x < s) red[threadIdx.x] = fmaxf(red[threadIdx.x], red[threadIdx.x + s]);
    __syncthreads();
  }
  const float M = red[0]; __syncthreads();
  float s_ = 0.f;
  for (int j = threadIdx.x; j < nt; j += 256)
    s_ += psum[(size_t)r * nt + j] * __expf(pmax[(size_t)r * nt + j] - M);
  red[threadIdx.x] = s_; __syncthreads();
  for (int s = 128; s > 0; s >>= 1) {
    if (threadIdx.x < s) red[threadIdx.x] += red[threadIdx.x + s];
    __syncthreads();
  }
  if (threadIdx.x == 0) lse[r] = M + logf(red[0]);
}

__global__ void finalize_kernel(float* __restrict__ out, const float* __restrict__ lse) {
  const long n4 = 16384000;
  for (long i = (long)blockIdx.x * blockDim.x + threadIdx.x; i < n4;
       i += (long)gridDim.x * blockDim.x) {
    float4 v = ((float4*)out)[i];
    float L = lse[i / 8000];
    v.x -= L; v.y -= L; v.z -= L; v.w -= L;
    ((float4*)out)[i] = v;
  }
}

// ---------------------------------------------------------------------------
extern "C" void kernel_launch(void* const* d_in, const int* in_sizes, int n_in,
                              void* d_out, int out_size, void* d_ws, size_t ws_size,
                              hipStream_t stream) {
  const int* trg = (const int*)d_in[0];
  const float* enc = (const float*)d_in[1];
  const float* emb = (const float*)d_in[2];
  const float* W_ih0 = (const float*)d_in[3];
  const float* W_hh0 = (const float*)d_in[4];
  const float* b_ih0 = (const float*)d_in[5];
  const float* b_hh0 = (const float*)d_in[6];
  const float* W_ih1 = (const float*)d_in[7];
  const float* W_hh1 = (const float*)d_in[8];
  const float* b_ih1 = (const float*)d_in[9];
  const float* b_hh1 = (const float*)d_in[10];
  const float* Wa = (const float*)d_in[11];
  const float* ba = (const float*)d_in[12];
  const float* Wh = (const float*)d_in[13];
  const float* bh = (const float*)d_in[14];
  const float* Wo = (const float*)d_in[15];
  const float* bo = (const float*)d_in[16];
  const float* Wp = (const float*)d_in[17];
  const float* bp = (const float*)d_in[18];
  const float* b_out = (const float*)d_in[19];
  float* out = (float*)d_out;

  unsigned char* ws = (unsigned char*)d_ws;
  size_t off = 0;
  auto alloc = [&](size_t bytes) -> void* {
    void* p = ws + off; off += (bytes + 255) & ~(size_t)255; return p;
  };
  u16* emb_b = (u16*)alloc(32768000);      // [32000][512]
  u16* trgemb_b = (u16*)alloc(2097152);    // [2048][512]
  u16* enc_b = (u16*)alloc(4194304);       // [2048][1024]
  u16* Wemb0_b = (u16*)alloc(2097152);     // [2048][512]
  u16* Wcat0_b = (u16*)alloc(6291456);     // [2048][1536]
  u16* Wcat1_b = (u16*)alloc(4194304);     // [2048][1024]
  u16* Wa_b = (u16*)alloc(1048576);        // [512][1024]
  u16* WhT_b = (u16*)alloc(524288);        // [512][512] k-major
  u16* Wp_b = (u16*)alloc(1572864);        // [512][1536]
  u16* xW0_b = (u16*)alloc(8388608);       // [2048][2048]
  float* annot = (float*)alloc(4194304);   // [2048][512] f32
  u16* scoresb = (u16*)alloc(6291456);     // [2048][1536]
  u16* pen_b = (u16*)alloc(2097152);       // [2048][512]
  u16* ctxb = (u16*)alloc(65536);          // [32][1024]
  u16* h0b = (u16*)alloc(65536);           // [2][32][512]
  u16* h1b = (u16*)alloc(65536);           // [2][32][512]
  float* c0 = (float*)alloc(65536);        // [32][512]
  float* c1 = (float*)alloc(65536);
  float* pmax = (float*)alloc(4194304);    // [2048][500] f32 (aliases annot_bt)
  float* psum = (float*)alloc(4194304);    // [2048][500] f32 (aliases enc_bt)
  float* lse = (float*)alloc(8192);
  if (off > ws_size) return;

  u16* annot_bt = (u16*)pmax;   // [32][64][512] bf16 = 2 MB
  u16* enc_bt = (u16*)psum;     // [32][64][1024] bf16 = 4 MB

  hipMemsetAsync(ctxb, 0, 65536, stream);
  hipMemsetAsync(h0b, 0, 65536, stream);
  hipMemsetAsync(h1b, 0, 65536, stream);
  hipMemsetAsync(c0, 0, 65536, stream);
  hipMemsetAsync(c1, 0, 65536, stream);

  // conversions / prep
  f2b4_kernel<<<1024, 256, 0, stream>>>(emb, emb_b, 4096000);
  f2b4_kernel<<<256, 256, 0, stream>>>(enc, enc_b, 524288);
  f2b4_kernel<<<128, 256, 0, stream>>>(Wa, Wa_b, 131072);
  f2b4_kernel<<<128, 256, 0, stream>>>(Wp, Wp_b, 196608);
  whT_kernel<<<512, 512, 0, stream>>>(Wh, WhT_b);
  f2b4_strided<<<512, 256, 0, stream>>>(W_ih0, Wemb0_b, 2048, 128, 1536, 0, 512, 0);
  f2b4_strided<<<512, 256, 0, stream>>>(W_ih0, Wcat0_b, 2048, 256, 1536, 512, 1536, 0);
  f2b4_strided<<<512, 256, 0, stream>>>(W_hh0, Wcat0_b, 2048, 128, 512, 0, 1536, 1024);
  f2b4_strided<<<512, 256, 0, stream>>>(W_ih1, Wcat1_b, 2048, 128, 512, 0, 1024, 0);
  f2b4_strided<<<512, 256, 0, stream>>>(W_hh1, Wcat1_b, 2048, 128, 512, 0, 1024, 512);
  gather_emb_kernel<<<2048, 128, 0, stream>>>(trg, emb, trgemb_b);
  enc_tr_kernel<<<2048, 256, 0, stream>>>(enc, enc_bt);

  // xW0 = trg_emb @ W_ih0[:, :512]^T + b_ih0 + b_hh0   (bf16 out)
  gemm_bt<1><<<dim3(16, 32), 256, 0, stream>>>(trgemb_b, Wemb0_b, nullptr, xW0_b,
                                               b_ih0, b_hh0, 2048, 512, 0, nullptr, nullptr);
  // annot = enc @ Wa^T + ba   (f32 out), then per-batch bf16 transpose
  gemm_bt<0><<<dim3(16, 8), 256, 0, stream>>>(enc_b, Wa_b, annot, nullptr,
                                              ba, nullptr, 512, 1024, 0, nullptr, nullptr);
  annot_tr_kernel<<<2048, 128, 0, stream>>>(annot, annot_bt);

  // recurrent scan: 3 kernels per step, hardware sync via kernel boundaries
  float* dout_hc = out + 65536000;
  for (int t = 0; t < 64; ++t) {
    const int p = t & 1;
    const u16* h0r = h0b + p * 16384;
    u16* h0w = h0b + (p ^ 1) * 16384;
    const u16* h1r = h1b + p * 16384;
    u16* h1w = h1b + (p ^ 1) * 16384;
    kA<<<32, 512, 0, stream>>>(xW0_b, Wcat0_b, ctxb, h0r, h0w, c0, dout_hc, t);
    kB<<<32, 512, 0, stream>>>(Wcat1_b, h0w, h1r, h1w, c1, b_ih1, b_hh1, scoresb, dout_hc, t);
    kC<<<32, 512, 0, stream>>>(WhT_b, bh, Wo, bo, annot_bt, enc_bt, h1w, ctxb, scoresb, t);
  }

  // pen = stacked @ Wp^T + bp   (bf16 out)
  gemm_bt<1><<<dim3(16, 8), 256, 0, stream>>>(scoresb, Wp_b, nullptr, pen_b,
                                              bp, nullptr, 512, 1536, 0, nullptr, nullptr);
  // logits = pen @ emb^T + b_out  (+ logsumexp partials)
  gemm_bt<2><<<dim3(16, 500), 256, 0, stream>>>(pen_b, emb_b, out, nullptr,
                                                b_out, nullptr, 32000, 512, 500, pmax, psum);
  lse_kernel<<<2048, 256, 0, stream>>>(pmax, psum, lse, 500);
  finalize_kernel<<<2048, 256, 0, stream>>>(out, lse);
}